// Round 5
// baseline (3087.064 us; speedup 1.0000x reference)
//
#include <hip/hip_runtime.h>

// ---- problem constants ----
#define BT      32768     // B*T = 128*256
#define T_SEQ   256
#define E_DIM   384
#define NH      6
#define NL      6
#define VOC     65
#define FF_DIM  1536
#define QKV_N   1152      // 3*E

typedef short bf16x8 __attribute__((ext_vector_type(8)));   // 8 bf16 (4 VGPRs)
typedef float f32x4  __attribute__((ext_vector_type(4)));
typedef unsigned short u16;

__device__ __forceinline__ u16 f2bf(float x) {              // RNE fp32->bf16
  unsigned u = __builtin_bit_cast(unsigned, x);
  u += 0x7fffu + ((u >> 16) & 1u);
  return (u16)(u >> 16);
}
__device__ __forceinline__ float bf2f(u16 v) {
  unsigned u = ((unsigned)v) << 16;
  return __builtin_bit_cast(float, u);
}

// ---------------- unified LDS-tiled transpose: src[b][R][C] fp32 -> dst bf16 [.. C][R] ----------------
__global__ __launch_bounds__(256) void transpose_t(
    const float* __restrict__ src, u16* __restrict__ dst, int R, int C,
    long sbs, long dbs_outer, int inner, long dbs_inner, long dbase) {
  __shared__ float t[32][33];
  const int b = blockIdx.z;
  const float* s = src + (long)b * sbs;
  u16* d = dst + dbase + (long)(b / inner) * dbs_outer + (long)(b % inner) * dbs_inner;
  const int r0 = blockIdx.x * 32, c0 = blockIdx.y * 32;
  const int tx = threadIdx.x & 31, ty = threadIdx.x >> 5;   // 32 x 8
#pragma unroll
  for (int i = 0; i < 4; i++) {
    int rr = ty + i * 8;
    int r = r0 + rr, c = c0 + tx;
    if (r < R && c < C) t[rr][tx] = s[(long)r * C + c];
  }
  __syncthreads();
#pragma unroll
  for (int i = 0; i < 4; i++) {
    int cc = ty + i * 8;
    int c = c0 + cc, r = r0 + tx;
    if (c < C && r < R) d[(long)c * R + r] = f2bf(t[tx][cc]);
  }
}

// ---------------- embedding (bf16 out) ----------------
__global__ __launch_bounds__(256) void embed_k(const int* __restrict__ idx,
                                               const float* __restrict__ tok,
                                               const float* __restrict__ pos,
                                               u16* __restrict__ x) {
  int i = blockIdx.x * 256 + threadIdx.x;        // over BT*48 groups of 8
  int bt = i / 48, q = i - bt * 48;
  int t = bt & 255;
  const float4* tp = (const float4*)(tok + (size_t)idx[bt] * E_DIM + q * 8);
  const float4* pp = (const float4*)(pos + (size_t)t * E_DIM + q * 8);
  float4 a0 = tp[0], a1 = tp[1], p0 = pp[0], p1 = pp[1];
  u16 o[8];
  o[0] = f2bf(a0.x + p0.x); o[1] = f2bf(a0.y + p0.y);
  o[2] = f2bf(a0.z + p0.z); o[3] = f2bf(a0.w + p0.w);
  o[4] = f2bf(a1.x + p1.x); o[5] = f2bf(a1.y + p1.y);
  o[6] = f2bf(a1.z + p1.z); o[7] = f2bf(a1.w + p1.w);
  *(bf16x8*)(x + (size_t)bt * E_DIM + q * 8) = *(bf16x8*)o;
}

// ---------------- layernorm (bf16 in -> bf16 out, fp32 math) ----------------
__global__ __launch_bounds__(256) void ln_k(const u16* __restrict__ x,
                                            const float* __restrict__ gam,
                                            const float* __restrict__ bet,
                                            u16* __restrict__ out) {
  int tid = threadIdx.x, lane = tid & 63, w = tid >> 6;
  size_t token = (size_t)blockIdx.x * 4 + w;
  const u16* xr = x + token * E_DIM;
  u16 raw[6];
  *(uint2*)raw          = *(const uint2*)(xr + 4 * lane);
  *(unsigned*)(raw + 4) = *(const unsigned*)(xr + 256 + 2 * lane);
  float v[6]; float s = 0.f;
#pragma unroll
  for (int i = 0; i < 6; i++) { v[i] = bf2f(raw[i]); s += v[i]; }
#pragma unroll
  for (int d = 1; d < 64; d <<= 1) s += __shfl_xor(s, d);
  float mean = s * (1.f / E_DIM);
  float q = 0.f;
#pragma unroll
  for (int i = 0; i < 6; i++) { float d0 = v[i] - mean; q += d0 * d0; }
#pragma unroll
  for (int d = 1; d < 64; d <<= 1) q += __shfl_xor(q, d);
  float r = rsqrtf(q * (1.f / E_DIM) + 1e-5f);
  int e[6] = {4 * lane, 4 * lane + 1, 4 * lane + 2, 4 * lane + 3,
              256 + 2 * lane, 256 + 2 * lane + 1};
  u16 o[6];
#pragma unroll
  for (int i = 0; i < 6; i++)
    o[i] = f2bf((v[i] - mean) * r * gam[e[i]] + bet[e[i]]);
  u16* orow = out + token * E_DIM;
  *(uint2*)(orow + 4 * lane)          = *(uint2*)o;
  *(unsigned*)(orow + 256 + 2 * lane) = *(unsigned*)(o + 4);
}

// ---------------- barrier-free MFMA GEMM: C[M][N] = A[M][K](bf16) @ Bt[N][K](bf16)^T ----
// Each wave independently computes a 64x64 tile; A/B fragments loaded DIRECTLY from
// global (no LDS staging, no __syncthreads anywhere). 2-deep register pipeline: the
// compiler tracks load->MFMA deps with per-register vmcnt(N), so loads stay in flight
// through the MFMA stream (the barrier-drain problem of the staged version is gone).
// Epilogue: per-wave private LDS repack for coalesced 16B bf16 stores (+bias/relu/resid).
__global__ __launch_bounds__(256) void gemm_nb(
    const u16* __restrict__ A, const u16* __restrict__ Bt, int K, int Nstore,
    const float* __restrict__ bias, const u16* __restrict__ resid,
    u16* __restrict__ outH, float* __restrict__ outF, int relu) {
  __shared__ u16 cb[4][64 * 68];              // per-wave repack buffer (pad 68)
  const int tid = threadIdx.x, lane = tid & 63, wv = tid >> 6;
  const int quad = lane >> 4, l16 = lane & 15;
  const int m0 = blockIdx.x * 128 + (wv & 1) * 64;   // waves 0,2 share A rows (L1 reuse)
  const int n0 = blockIdx.y * 128 + (wv >> 1) * 64;  // waves 0,1 share B rows
  const u16* Ap = A  + (size_t)(m0 + l16) * K + quad * 8;
  const u16* Bp = Bt + (size_t)(n0 + l16) * K + quad * 8;

  f32x4 acc[4][4];
#pragma unroll
  for (int i = 0; i < 4; i++)
#pragma unroll
    for (int j = 0; j < 4; j++) acc[i][j] = (f32x4){0.f, 0.f, 0.f, 0.f};

  bf16x8 a0[4], b0[4], a1[4], b1[4];
#pragma unroll
  for (int i = 0; i < 4; i++) a0[i] = *(const bf16x8*)(Ap + (size_t)(i * 16) * K);
#pragma unroll
  for (int j = 0; j < 4; j++) b0[j] = *(const bf16x8*)(Bp + (size_t)(j * 16) * K);

  for (int k0 = 0; k0 < K; k0 += 64) {        // K%64==0 (384 or 1536)
#pragma unroll
    for (int i = 0; i < 4; i++) a1[i] = *(const bf16x8*)(Ap + (size_t)(i * 16) * K + k0 + 32);
#pragma unroll
    for (int j = 0; j < 4; j++) b1[j] = *(const bf16x8*)(Bp + (size_t)(j * 16) * K + k0 + 32);
#pragma unroll
    for (int i = 0; i < 4; i++)
#pragma unroll
      for (int j = 0; j < 4; j++)
        acc[i][j] = __builtin_amdgcn_mfma_f32_16x16x32_bf16(a0[i], b0[j], acc[i][j], 0, 0, 0);
    if (k0 + 64 < K) {
#pragma unroll
      for (int i = 0; i < 4; i++) a0[i] = *(const bf16x8*)(Ap + (size_t)(i * 16) * K + k0 + 64);
#pragma unroll
      for (int j = 0; j < 4; j++) b0[j] = *(const bf16x8*)(Bp + (size_t)(j * 16) * K + k0 + 64);
    }
#pragma unroll
    for (int i = 0; i < 4; i++)
#pragma unroll
      for (int j = 0; j < 4; j++)
        acc[i][j] = __builtin_amdgcn_mfma_f32_16x16x32_bf16(a1[i], b1[j], acc[i][j], 0, 0, 0);
  }

  if (outH) {
    u16* L = cb[wv];
    // scatter C-layout (row = i*16+quad*4+r, col = j*16+l16) into private LDS tile
#pragma unroll
    for (int j = 0; j < 4; j++) {
      int gn = n0 + j * 16 + l16;
      float bv = bias ? bias[gn] : 0.f;
#pragma unroll
      for (int i = 0; i < 4; i++)
#pragma unroll
        for (int r = 0; r < 4; r++) {
          float v = acc[i][j][r] + bv;
          if (relu) v = fmaxf(v, 0.f);
          L[(i * 16 + quad * 4 + r) * 68 + j * 16 + l16] = f2bf(v);
        }
    }
    // sweep: 8 passes, 8 rows x 128B coalesced 16B/lane stores (wave-private, no barrier)
    const int sr = lane >> 3, seg = (lane & 7) * 8;
#pragma unroll
    for (int s = 0; s < 8; s++) {
      int row = s * 8 + sr;
      u16 pk[8];
      *(uint4*)pk = *(const uint4*)&L[row * 68 + seg];
      size_t o = (size_t)(m0 + row) * Nstore + n0 + seg;
      if (resid) {
        u16 rv[8];
        *(uint4*)rv = *(const uint4*)&resid[o];
#pragma unroll
        for (int q2 = 0; q2 < 8; q2++) pk[q2] = f2bf(bf2f(pk[q2]) + bf2f(rv[q2]));
      }
      *(uint4*)&outH[o] = *(uint4*)pk;
    }
  } else {
    // fp32 path (logits, N=65)
#pragma unroll
    for (int j = 0; j < 4; j++) {
      const int gn = n0 + j * 16 + l16;
      if (gn < Nstore) {
        const float bv = bias ? bias[gn] : 0.f;
#pragma unroll
        for (int i = 0; i < 4; i++)
#pragma unroll
          for (int r = 0; r < 4; r++) {
            const int gm = m0 + i * 16 + quad * 4 + r;
            outF[(size_t)gm * Nstore + gn] = acc[i][j][r] + bv;
          }
      }
    }
  }
}

// ---------------- fused causal attention ----------------
__global__ __launch_bounds__(512) void attn_k(const u16* __restrict__ qkv,
                                              u16* __restrict__ att) {
  __shared__ u16 Kc[64 * 64];
  __shared__ u16 Vtc[64 * 64];
  __shared__ u16 Pl[8 * 32 * 64];
  const int b = blockIdx.x / NH, h = blockIdx.x % NH;
  const int tid = threadIdx.x, lane = tid & 63, w = tid >> 6;
  const int quad = lane >> 4, l16 = lane & 15;
  const int rowb = b * T_SEQ;

  bf16x8 qf[2][2];
#pragma unroll
  for (int mi = 0; mi < 2; mi++)
#pragma unroll
    for (int kk = 0; kk < 2; kk++)
      qf[mi][kk] = *(const bf16x8*)(qkv + (size_t)(rowb + w * 32 + mi * 16 + l16) * QKV_N +
                                    h * 64 + kk * 32 + quad * 8);

  f32x4 Oa[2][4];
  float mrun[2][4], lrun[2][4];
#pragma unroll
  for (int mi = 0; mi < 2; mi++) {
#pragma unroll
    for (int di = 0; di < 4; di++) Oa[mi][di] = (f32x4){0.f, 0.f, 0.f, 0.f};
#pragma unroll
    for (int r = 0; r < 4; r++) { mrun[mi][r] = -1e30f; lrun[mi][r] = 0.f; }
  }

  u16* Pw = &Pl[w * 2048];
  const int nch = (w >> 1) + 1;
  const int sr = tid >> 3, sseg = (tid & 7) * 8;

  for (int c = 0; c < 4; c++) {
    const int s0 = c * 64;
    __syncthreads();
    *(uint4*)&Kc[sr * 64 + sseg] =
        *(const uint4*)(qkv + (size_t)(rowb + s0 + sr) * QKV_N + 384 + h * 64 + sseg);
    {
      union { uint4 u; u16 us[8]; } tb;
      tb.u = *(const uint4*)(qkv + (size_t)(rowb + s0 + sr) * QKV_N + 768 + h * 64 + sseg);
#pragma unroll
      for (int j = 0; j < 8; j++) Vtc[(sseg + j) * 64 + sr] = tb.us[j];
    }
    __syncthreads();
    if (c >= nch) continue;

    f32x4 S[2][4];
    bf16x8 kf[4][2];
#pragma unroll
    for (int ni = 0; ni < 4; ni++)
#pragma unroll
      for (int kk = 0; kk < 2; kk++)
        kf[ni][kk] = *(const bf16x8*)&Kc[(ni * 16 + l16) * 64 + kk * 32 + quad * 8];
#pragma unroll
    for (int mi = 0; mi < 2; mi++)
#pragma unroll
      for (int ni = 0; ni < 4; ni++) {
        f32x4 z = (f32x4){0.f, 0.f, 0.f, 0.f};
        z = __builtin_amdgcn_mfma_f32_16x16x32_bf16(qf[mi][0], kf[ni][0], z, 0, 0, 0);
        S[mi][ni] = __builtin_amdgcn_mfma_f32_16x16x32_bf16(qf[mi][1], kf[ni][1], z, 0, 0, 0);
      }
    const bool diag = (c == nch - 1);
#pragma unroll
    for (int mi = 0; mi < 2; mi++)
#pragma unroll
      for (int ni = 0; ni < 4; ni++)
#pragma unroll
        for (int r = 0; r < 4; r++) {
          float xv = S[mi][ni][r] * 0.125f;
          if (diag) {
            int t = w * 32 + mi * 16 + quad * 4 + r;
            int s = s0 + ni * 16 + l16;
            if (s > t) xv = -1e30f;
          }
          S[mi][ni][r] = xv;
        }
#pragma unroll
    for (int mi = 0; mi < 2; mi++)
#pragma unroll
      for (int r = 0; r < 4; r++) {
        float mx = fmaxf(fmaxf(S[mi][0][r], S[mi][1][r]), fmaxf(S[mi][2][r], S[mi][3][r]));
        mx = fmaxf(mx, __shfl_xor(mx, 1));
        mx = fmaxf(mx, __shfl_xor(mx, 2));
        mx = fmaxf(mx, __shfl_xor(mx, 4));
        mx = fmaxf(mx, __shfl_xor(mx, 8));
        float mnew = fmaxf(mrun[mi][r], mx);
        float alpha = __expf(mrun[mi][r] - mnew);
        float ls = 0.f;
#pragma unroll
        for (int ni = 0; ni < 4; ni++) {
          float p = __expf(S[mi][ni][r] - mnew);
          S[mi][ni][r] = p; ls += p;
        }
        ls += __shfl_xor(ls, 1); ls += __shfl_xor(ls, 2);
        ls += __shfl_xor(ls, 4); ls += __shfl_xor(ls, 8);
        lrun[mi][r] = lrun[mi][r] * alpha + ls;
        mrun[mi][r] = mnew;
#pragma unroll
        for (int di = 0; di < 4; di++) Oa[mi][di][r] *= alpha;
      }
#pragma unroll
    for (int mi = 0; mi < 2; mi++)
#pragma unroll
      for (int ni = 0; ni < 4; ni++)
#pragma unroll
        for (int r = 0; r < 4; r++)
          Pw[(mi * 16 + quad * 4 + r) * 64 + ni * 16 + l16] = f2bf(S[mi][ni][r]);
    bf16x8 pf[2][2], vf[4][2];
#pragma unroll
    for (int mi = 0; mi < 2; mi++)
#pragma unroll
      for (int kk = 0; kk < 2; kk++)
        pf[mi][kk] = *(const bf16x8*)&Pw[(mi * 16 + l16) * 64 + kk * 32 + quad * 8];
#pragma unroll
    for (int di = 0; di < 4; di++)
#pragma unroll
      for (int kk = 0; kk < 2; kk++)
        vf[di][kk] = *(const bf16x8*)&Vtc[(di * 16 + l16) * 64 + kk * 32 + quad * 8];
#pragma unroll
    for (int mi = 0; mi < 2; mi++)
#pragma unroll
      for (int di = 0; di < 4; di++) {
        Oa[mi][di] = __builtin_amdgcn_mfma_f32_16x16x32_bf16(pf[mi][0], vf[di][0], Oa[mi][di], 0, 0, 0);
        Oa[mi][di] = __builtin_amdgcn_mfma_f32_16x16x32_bf16(pf[mi][1], vf[di][1], Oa[mi][di], 0, 0, 0);
      }
  }

#pragma unroll
  for (int mi = 0; mi < 2; mi++)
#pragma unroll
    for (int r = 0; r < 4; r++) {
      float inv = 1.f / lrun[mi][r];
      int t = w * 32 + mi * 16 + quad * 4 + r;
#pragma unroll
      for (int di = 0; di < 4; di++)
        att[(size_t)(rowb + t) * E_DIM + h * 64 + di * 16 + l16] = f2bf(Oa[mi][di][r] * inv);
    }
}

// ---------------- loss: grid-stride, 1 atomic per block ----------------
__global__ __launch_bounds__(256) void loss_k(const float* __restrict__ logits,
                                              const int* __restrict__ tgt,
                                              float* __restrict__ loss) {
  __shared__ float part[4];
  const int tid = threadIdx.x, lane = tid & 63, w = tid >> 6;
  const int wave_id = blockIdx.x * 4 + w;          // 512 blocks -> 2048 waves
  float acc = 0.f;
  for (int t = wave_id; t < BT; t += 2048) {
    const float* row = logits + (size_t)t * VOC;
    float a = row[lane];
    float b = (lane == 0) ? row[64] : -1e30f;
    float mx = fmaxf(a, b);
#pragma unroll
    for (int d = 1; d < 64; d <<= 1) mx = fmaxf(mx, __shfl_xor(mx, d));
    float sum = __expf(a - mx) + ((lane == 0) ? __expf(b - mx) : 0.f);
#pragma unroll
    for (int d = 1; d < 64; d <<= 1) sum += __shfl_xor(sum, d);
    if (lane == 0) acc += mx + __logf(sum) - row[tgt[t]];
  }
  if (lane == 0) part[w] = acc;
  __syncthreads();
  if (tid == 0)
    atomicAdd(loss, (part[0] + part[1] + part[2] + part[3]) * (1.f / (float)BT));
}

// ---------------- host ----------------
extern "C" void kernel_launch(void* const* d_in, const int* in_sizes, int n_in,
                              void* d_out, int out_size, void* d_ws, size_t ws_size,
                              hipStream_t stream) {
  (void)in_sizes; (void)n_in; (void)out_size; (void)ws_size;
  const int*   idx  = (const int*)d_in[0];
  const int*   tgt  = (const int*)d_in[1];
  const float* tok  = (const float*)d_in[2];
  const float* pos  = (const float*)d_in[3];
  const float* Wq   = (const float*)d_in[4];
  const float* Wk   = (const float*)d_in[5];
  const float* Wv   = (const float*)d_in[6];
  const float* Wo   = (const float*)d_in[7];
  const float* bo   = (const float*)d_in[8];
  const float* ln1s = (const float*)d_in[9];
  const float* ln1b = (const float*)d_in[10];
  const float* ln2s = (const float*)d_in[11];
  const float* ln2b = (const float*)d_in[12];
  const float* W1   = (const float*)d_in[13];
  const float* b1   = (const float*)d_in[14];
  const float* W2   = (const float*)d_in[15];
  const float* b2   = (const float*)d_in[16];
  const float* lnfs = (const float*)d_in[17];
  const float* lnfb = (const float*)d_in[18];
  const float* Wout = (const float*)d_in[19];
  const float* bout = (const float*)d_in[20];

  char* w = (char*)d_ws;
  u16* x      = (u16*)w;    w += (size_t)BT * E_DIM * 2;      // bf16 residual stream
  u16* hb     = (u16*)w;    w += (size_t)BT * E_DIM * 2;
  u16* attb   = (u16*)w;    w += (size_t)BT * E_DIM * 2;
  u16* big    = (u16*)w;    w += (size_t)BT * FF_DIM * 2;     // qkv / ff union
  u16* Wqkv_t = (u16*)w;    w += (size_t)NL * QKV_N * E_DIM * 2;
  u16* Wo_t   = (u16*)w;    w += (size_t)NL * E_DIM * E_DIM * 2;
  u16* W1_t   = (u16*)w;    w += (size_t)NL * FF_DIM * E_DIM * 2;
  u16* W2_t   = (u16*)w;    w += (size_t)NL * E_DIM * FF_DIM * 2;
  u16* Wout_t = (u16*)w;    w += (size_t)128 * E_DIM * 2;
  u16* qkv = big;
  u16* ff  = big;

  float* logits = (float*)d_out;
  float* loss   = logits + (size_t)BT * VOC;

  hipMemsetAsync(Wout_t, 0, 128 * E_DIM * 2, stream);
  transpose_t<<<dim3(12, 2, 36), 256, 0, stream>>>(Wq, Wqkv_t, 384, 64,
      24576, 442368, 6, 24576, 0);
  transpose_t<<<dim3(12, 2, 36), 256, 0, stream>>>(Wk, Wqkv_t, 384, 64,
      24576, 442368, 6, 24576, (long)384 * 384);
  transpose_t<<<dim3(12, 2, 36), 256, 0, stream>>>(Wv, Wqkv_t, 384, 64,
      24576, 442368, 6, 24576, (long)768 * 384);
  transpose_t<<<dim3(12, 12, 6), 256, 0, stream>>>(Wo, Wo_t, 384, 384,
      147456, 147456, 1, 0, 0);
  transpose_t<<<dim3(12, 48, 6), 256, 0, stream>>>(W1, W1_t, 384, 1536,
      589824, 589824, 1, 0, 0);
  transpose_t<<<dim3(48, 12, 6), 256, 0, stream>>>(W2, W2_t, 1536, 384,
      589824, 589824, 1, 0, 0);
  transpose_t<<<dim3(12, 3, 1), 256, 0, stream>>>(Wout, Wout_t, 384, 65,
      0, 0, 1, 0, 0);

  embed_k<<<6144, 256, 0, stream>>>(idx, tok, pos, x);

  for (int l = 0; l < NL; l++) {
    ln_k<<<8192, 256, 0, stream>>>(x, ln1s + l * E_DIM, ln1b + l * E_DIM, hb);
    gemm_nb<<<dim3(256, 9), 256, 0, stream>>>(hb, Wqkv_t + (size_t)l * QKV_N * E_DIM,
                                              384, QKV_N, nullptr, nullptr, qkv, nullptr, 0);
    attn_k<<<768, 512, 0, stream>>>(qkv, attb);
    gemm_nb<<<dim3(256, 3), 256, 0, stream>>>(attb, Wo_t + (size_t)l * E_DIM * E_DIM,
                                              384, E_DIM, bo + l * E_DIM, x, x, nullptr, 0);
    ln_k<<<8192, 256, 0, stream>>>(x, ln2s + l * E_DIM, ln2b + l * E_DIM, hb);
    gemm_nb<<<dim3(256, 12), 256, 0, stream>>>(hb, W1_t + (size_t)l * FF_DIM * E_DIM,
                                               384, FF_DIM, b1 + l * FF_DIM, nullptr, ff, nullptr, 1);
    gemm_nb<<<dim3(256, 3), 256, 0, stream>>>(ff, W2_t + (size_t)l * E_DIM * FF_DIM,
                                              1536, E_DIM, b2 + l * E_DIM, x, x, nullptr, 0);
  }
  ln_k<<<8192, 256, 0, stream>>>(x, lnfs, lnfb, hb);
  gemm_nb<<<dim3(256, 1), 256, 0, stream>>>(hb, Wout_t, 384, VOC, bout, nullptr, nullptr, logits, 0);

  hipMemsetAsync(loss, 0, 4, stream);
  loss_k<<<512, 256, 0, stream>>>(logits, tgt, loss);
}